// Round 1
// baseline (1432.141 us; speedup 1.0000x reference)
//
#include <hip/hip_runtime.h>

// ChebNet: K=3 ChebConv x2 + 2-layer MLP head. fp32 baseline.
// features[N,64], src/dst[E], W1[192,64], b1[64], W2[192,64], b2[64],
// Wm1[64,64], bm1[64], Wm2[64,32], bm2[32] -> out[N,32]

__global__ void k_deg(const int* __restrict__ dst, float* __restrict__ deg, int E) {
    int e = blockIdx.x * blockDim.x + threadIdx.x;
    if (e < E) atomicAdd(&deg[dst[e]], 1.0f);
}

__global__ void k_dinv(float* deg, int N) {
    int i = blockIdx.x * blockDim.x + threadIdx.x;
    if (i < N) deg[i] = rsqrtf(fmaxf(deg[i], 1.0f));
}

// one wave per edge: agg[dst,:] += X[src,:] * dinv[src]
__global__ __launch_bounds__(256) void k_scatter(
    const float* __restrict__ X, const int* __restrict__ src,
    const int* __restrict__ dst, const float* __restrict__ dinv,
    float* __restrict__ agg, int E) {
    int wid = (blockIdx.x * blockDim.x + threadIdx.x) >> 6;
    int lane = threadIdx.x & 63;
    if (wid >= E) return;
    int s = src[wid];
    int d = dst[wid];
    float v = X[(size_t)s * 64 + lane] * dinv[s];
    atomicAdd(&agg[(size_t)d * 64 + lane], v);
}

// X1 = -dinv * agg   (elementwise over N*64, float4)
__global__ void k_x1(const float4* __restrict__ agg, const float* __restrict__ dinv,
                     float4* __restrict__ X1, int n4) {
    int idx = blockIdx.x * blockDim.x + threadIdx.x;
    if (idx >= n4) return;
    int node = idx >> 4;
    float s = -dinv[node];
    float4 a = agg[idx];
    X1[idx] = make_float4(s * a.x, s * a.y, s * a.z, s * a.w);
}

// X2 = -2*dinv*agg - X0
__global__ void k_x2(const float4* __restrict__ agg, const float* __restrict__ dinv,
                     const float4* __restrict__ X0, float4* __restrict__ X2, int n4) {
    int idx = blockIdx.x * blockDim.x + threadIdx.x;
    if (idx >= n4) return;
    int node = idx >> 4;
    float s = -2.0f * dinv[node];
    float4 a = agg[idx];
    float4 x = X0[idx];
    X2[idx] = make_float4(fmaf(s, a.x, -x.x), fmaf(s, a.y, -x.y),
                          fmaf(s, a.z, -x.z), fmaf(s, a.w, -x.w));
}

// Y[N,64] = relu(X0@W[0:64] + X1@W[64:128] + X2@W[128:192] + b)
// wave per node, lane = output feature, W staged in LDS (48 KB)
__global__ __launch_bounds__(256) void k_cheb_lin(
    const float* __restrict__ X0, const float* __restrict__ X1,
    const float* __restrict__ X2, const float* __restrict__ W,
    const float* __restrict__ b, float* __restrict__ Y, int N) {
    __shared__ float Ws[192 * 64];
    __shared__ float bs[64];
    for (int i = threadIdx.x; i < 192 * 64; i += 256) Ws[i] = W[i];
    if (threadIdx.x < 64) bs[threadIdx.x] = b[threadIdx.x];
    __syncthreads();
    int lane = threadIdx.x & 63;
    int wave = threadIdx.x >> 6;
    for (int node = blockIdx.x * 4 + wave; node < N; node += gridDim.x * 4) {
        const float* x0 = X0 + (size_t)node * 64;
        const float* x1 = X1 + (size_t)node * 64;
        const float* x2 = X2 + (size_t)node * 64;
        float acc = bs[lane];
#pragma unroll 8
        for (int j = 0; j < 64; j++) {
            acc = fmaf(x0[j], Ws[j * 64 + lane], acc);
            acc = fmaf(x1[j], Ws[(64 + j) * 64 + lane], acc);
            acc = fmaf(x2[j], Ws[(128 + j) * 64 + lane], acc);
        }
        Y[(size_t)node * 64 + lane] = fmaxf(acc, 0.0f);
    }
}

// out[N,32] = relu(H@Wm1+bm1) @ Wm2 + bm2. Wave per node; hidden vec via
// wave-local LDS buffer (wave lockstep -> no block barrier needed).
__global__ __launch_bounds__(256) void k_mlp(
    const float* __restrict__ H, const float* __restrict__ Wm1,
    const float* __restrict__ bm1, const float* __restrict__ Wm2,
    const float* __restrict__ bm2, float* __restrict__ out, int N) {
    __shared__ float W1s[64 * 64];
    __shared__ float W2s[64 * 32];
    __shared__ float b1s[64];
    __shared__ float b2s[32];
    __shared__ float hb[4][64];
    for (int i = threadIdx.x; i < 64 * 64; i += 256) W1s[i] = Wm1[i];
    for (int i = threadIdx.x; i < 64 * 32; i += 256) W2s[i] = Wm2[i];
    if (threadIdx.x < 64) b1s[threadIdx.x] = bm1[threadIdx.x];
    else if (threadIdx.x < 96) b2s[threadIdx.x - 64] = bm2[threadIdx.x - 64];
    __syncthreads();
    int lane = threadIdx.x & 63;
    int wave = threadIdx.x >> 6;
    for (int node = blockIdx.x * 4 + wave; node < N; node += gridDim.x * 4) {
        const float* h = H + (size_t)node * 64;
        float acc = b1s[lane];
#pragma unroll 8
        for (int j = 0; j < 64; j++) acc = fmaf(h[j], W1s[j * 64 + lane], acc);
        acc = fmaxf(acc, 0.0f);
        hb[wave][lane] = acc;  // wave-lockstep: write then read below is ordered
        if (lane < 32) {
            float o = b2s[lane];
#pragma unroll 8
            for (int j = 0; j < 64; j++) o = fmaf(hb[wave][j], W2s[j * 32 + lane], o);
            out[(size_t)node * 32 + lane] = o;
        }
    }
}

extern "C" void kernel_launch(void* const* d_in, const int* in_sizes, int n_in,
                              void* d_out, int out_size, void* d_ws, size_t ws_size,
                              hipStream_t stream) {
    const float* features = (const float*)d_in[0];
    const int* src = (const int*)d_in[1];
    const int* dst = (const int*)d_in[2];
    const float* W1 = (const float*)d_in[4];
    const float* b1 = (const float*)d_in[5];
    const float* W2 = (const float*)d_in[6];
    const float* b2 = (const float*)d_in[7];
    const float* Wm1 = (const float*)d_in[8];
    const float* bm1 = (const float*)d_in[9];
    const float* Wm2 = (const float*)d_in[10];
    const float* bm2 = (const float*)d_in[11];
    float* out = (float*)d_out;

    int N = in_sizes[0] / 64;
    int E = in_sizes[1];
    int n4 = N * 16;

    float* ws = (float*)d_ws;
    float* dinv = ws;                       // [N]
    float* B1 = ws + N;                     // [N,64] X1
    float* B2 = B1 + (size_t)N * 64;        // [N,64] X2
    float* B3 = B2 + (size_t)N * 64;        // [N,64] agg / H2
    float* B4 = B3 + (size_t)N * 64;        // [N,64] H1
    size_t fbytes = (size_t)N * 64 * sizeof(float);

    int ethreads = (E + 255) / 256;
    int ewaves = (E + 3) / 4;
    int nblk = (N + 255) / 256;
    int eblk4 = (n4 + 255) / 256;

    // degree -> dinv (in place)
    hipMemsetAsync(dinv, 0, (size_t)N * sizeof(float), stream);
    k_deg<<<ethreads, 256, 0, stream>>>(dst, dinv, E);
    k_dinv<<<nblk, 256, 0, stream>>>(dinv, N);

    // ---- layer 1 (X0 = features) ----
    hipMemsetAsync(B3, 0, fbytes, stream);
    k_scatter<<<ewaves, 256, 0, stream>>>(features, src, dst, dinv, B3, E);
    k_x1<<<eblk4, 256, 0, stream>>>((const float4*)B3, dinv, (float4*)B1, n4);
    hipMemsetAsync(B3, 0, fbytes, stream);
    k_scatter<<<ewaves, 256, 0, stream>>>(B1, src, dst, dinv, B3, E);
    k_x2<<<eblk4, 256, 0, stream>>>((const float4*)B3, dinv, (const float4*)features,
                                    (float4*)B2, n4);
    k_cheb_lin<<<2048, 256, 0, stream>>>(features, B1, B2, W1, b1, B4, N);

    // ---- layer 2 (X0 = B4 = H1) ----
    hipMemsetAsync(B3, 0, fbytes, stream);
    k_scatter<<<ewaves, 256, 0, stream>>>(B4, src, dst, dinv, B3, E);
    k_x1<<<eblk4, 256, 0, stream>>>((const float4*)B3, dinv, (float4*)B1, n4);
    hipMemsetAsync(B3, 0, fbytes, stream);
    k_scatter<<<ewaves, 256, 0, stream>>>(B1, src, dst, dinv, B3, E);
    k_x2<<<eblk4, 256, 0, stream>>>((const float4*)B3, dinv, (const float4*)B4,
                                    (float4*)B2, n4);
    k_cheb_lin<<<2048, 256, 0, stream>>>(B4, B1, B2, W2, b2, B3, N);

    // ---- MLP head ----
    k_mlp<<<2048, 256, 0, stream>>>(B3, Wm1, bm1, Wm2, bm2, out, N);
}

// Round 2
// 883.982 us; speedup vs baseline: 1.6201x; 1.6201x over previous
//
#include <hip/hip_runtime.h>

// ChebNet fp32, round 2: CSR-gather aggregation (no float atomics).
// Build CSR by dst on device each call, then prop = per-node register
// accumulation with fused Chebyshev epilogue.

// ---------- CSR build ----------

__global__ void k_hist(const int* __restrict__ dst, int* __restrict__ cnt, int E) {
    int e = blockIdx.x * blockDim.x + threadIdx.x;
    if (e < E) atomicAdd(&cnt[dst[e]], 1);
}

__global__ void k_blocksum(const int* __restrict__ cnt, int* __restrict__ bsum, int N) {
    __shared__ int red[256];
    int i = blockIdx.x * 256 + threadIdx.x;
    red[threadIdx.x] = (i < N) ? cnt[i] : 0;
    __syncthreads();
    for (int s = 128; s > 0; s >>= 1) {
        if (threadIdx.x < s) red[threadIdx.x] += red[threadIdx.x + s];
        __syncthreads();
    }
    if (threadIdx.x == 0) bsum[blockIdx.x] = red[0];
}

// exclusive scan of bsum[0..nb), nb <= 1024, one block of 1024 threads
__global__ void k_scanbsum(int* bsum, int nb) {
    __shared__ int sh[1024];
    int tid = threadIdx.x;
    int v = (tid < nb) ? bsum[tid] : 0;
    sh[tid] = v;
    __syncthreads();
    for (int off = 1; off < 1024; off <<= 1) {
        int t = 0;
        if (tid >= off) t = sh[tid - off];
        __syncthreads();
        sh[tid] += t;
        __syncthreads();
    }
    if (tid < nb) bsum[tid] = sh[tid] - v;  // exclusive
}

// per-element exclusive scan + block offset -> row_ptr & cursor; also dinv.
__global__ void k_scanfinal(const int* __restrict__ cnt, const int* __restrict__ bsum,
                            int* __restrict__ row_ptr, int* __restrict__ cursor,
                            float* __restrict__ dinv, int N, int E) {
    __shared__ int sh[256];
    int i = blockIdx.x * 256 + threadIdx.x;
    int v = (i < N) ? cnt[i] : 0;
    sh[threadIdx.x] = v;
    __syncthreads();
    for (int off = 1; off < 256; off <<= 1) {
        int t = 0;
        if (threadIdx.x >= off) t = sh[threadIdx.x - off];
        __syncthreads();
        sh[threadIdx.x] += t;
        __syncthreads();
    }
    int excl = sh[threadIdx.x] - v + bsum[blockIdx.x];
    if (i < N) {
        row_ptr[i] = excl;
        cursor[i] = excl;
        dinv[i] = rsqrtf(fmaxf((float)v, 1.0f));
    }
    if (blockIdx.x == 0 && threadIdx.x == 0) row_ptr[N] = E;
}

__global__ void k_place(const int* __restrict__ src, const int* __restrict__ dst,
                        int* __restrict__ cursor, int* __restrict__ col, int E) {
    int e = blockIdx.x * blockDim.x + threadIdx.x;
    if (e < E) {
        int p = atomicAdd(&cursor[dst[e]], 1);
        col[p] = src[e];
    }
}

// ---------- propagation (gather) ----------
// MODE 1: OUT = -dinv[i] * sum_{s in in(i)} X[s]*dinv[s]
// MODE 2: OUT = -2*dinv[i]*sum - X0[i]
template <int MODE>
__global__ __launch_bounds__(256) void k_prop(
    const float* __restrict__ X, const int* __restrict__ rp,
    const int* __restrict__ col, const float* __restrict__ dinv,
    const float* __restrict__ X0, float* __restrict__ OUT, int N) {
    int wid = (blockIdx.x * blockDim.x + threadIdx.x) >> 6;
    int lane = threadIdx.x & 63;
    if (wid >= N) return;
    int beg = rp[wid], end = rp[wid + 1];
    float acc0 = 0.0f, acc1 = 0.0f;
    int e = beg;
    for (; e + 1 < end; e += 2) {
        int s0 = col[e], s1 = col[e + 1];
        float d0 = dinv[s0], d1 = dinv[s1];
        float x0 = X[(size_t)s0 * 64 + lane];
        float x1 = X[(size_t)s1 * 64 + lane];
        acc0 = fmaf(x0, d0, acc0);
        acc1 = fmaf(x1, d1, acc1);
    }
    if (e < end) {
        int s0 = col[e];
        acc0 = fmaf(X[(size_t)s0 * 64 + lane], dinv[s0], acc0);
    }
    float acc = acc0 + acc1;
    float di = dinv[wid];
    if (MODE == 1) {
        OUT[(size_t)wid * 64 + lane] = -di * acc;
    } else {
        OUT[(size_t)wid * 64 + lane] = fmaf(-2.0f * di, acc, -X0[(size_t)wid * 64 + lane]);
    }
}

// ---------- dense layers (unchanged from R1) ----------

__global__ __launch_bounds__(256) void k_cheb_lin(
    const float* __restrict__ X0, const float* __restrict__ X1,
    const float* __restrict__ X2, const float* __restrict__ W,
    const float* __restrict__ b, float* __restrict__ Y, int N) {
    __shared__ float Ws[192 * 64];
    __shared__ float bs[64];
    for (int i = threadIdx.x; i < 192 * 64; i += 256) Ws[i] = W[i];
    if (threadIdx.x < 64) bs[threadIdx.x] = b[threadIdx.x];
    __syncthreads();
    int lane = threadIdx.x & 63;
    int wave = threadIdx.x >> 6;
    for (int node = blockIdx.x * 4 + wave; node < N; node += gridDim.x * 4) {
        const float* x0 = X0 + (size_t)node * 64;
        const float* x1 = X1 + (size_t)node * 64;
        const float* x2 = X2 + (size_t)node * 64;
        float acc = bs[lane];
#pragma unroll 8
        for (int j = 0; j < 64; j++) {
            acc = fmaf(x0[j], Ws[j * 64 + lane], acc);
            acc = fmaf(x1[j], Ws[(64 + j) * 64 + lane], acc);
            acc = fmaf(x2[j], Ws[(128 + j) * 64 + lane], acc);
        }
        Y[(size_t)node * 64 + lane] = fmaxf(acc, 0.0f);
    }
}

__global__ __launch_bounds__(256) void k_mlp(
    const float* __restrict__ H, const float* __restrict__ Wm1,
    const float* __restrict__ bm1, const float* __restrict__ Wm2,
    const float* __restrict__ bm2, float* __restrict__ out, int N) {
    __shared__ float W1s[64 * 64];
    __shared__ float W2s[64 * 32];
    __shared__ float b1s[64];
    __shared__ float b2s[32];
    __shared__ float hb[4][64];
    for (int i = threadIdx.x; i < 64 * 64; i += 256) W1s[i] = Wm1[i];
    for (int i = threadIdx.x; i < 64 * 32; i += 256) W2s[i] = Wm2[i];
    if (threadIdx.x < 64) b1s[threadIdx.x] = bm1[threadIdx.x];
    else if (threadIdx.x < 96) b2s[threadIdx.x - 64] = bm2[threadIdx.x - 64];
    __syncthreads();
    int lane = threadIdx.x & 63;
    int wave = threadIdx.x >> 6;
    for (int node = blockIdx.x * 4 + wave; node < N; node += gridDim.x * 4) {
        const float* h = H + (size_t)node * 64;
        float acc = b1s[lane];
#pragma unroll 8
        for (int j = 0; j < 64; j++) acc = fmaf(h[j], W1s[j * 64 + lane], acc);
        acc = fmaxf(acc, 0.0f);
        hb[wave][lane] = acc;
        if (lane < 32) {
            float o = b2s[lane];
#pragma unroll 8
            for (int j = 0; j < 64; j++) o = fmaf(hb[wave][j], W2s[j * 32 + lane], o);
            out[(size_t)node * 32 + lane] = o;
        }
    }
}

extern "C" void kernel_launch(void* const* d_in, const int* in_sizes, int n_in,
                              void* d_out, int out_size, void* d_ws, size_t ws_size,
                              hipStream_t stream) {
    const float* features = (const float*)d_in[0];
    const int* src = (const int*)d_in[1];
    const int* dst = (const int*)d_in[2];
    const float* W1 = (const float*)d_in[4];
    const float* b1 = (const float*)d_in[5];
    const float* W2 = (const float*)d_in[6];
    const float* b2 = (const float*)d_in[7];
    const float* Wm1 = (const float*)d_in[8];
    const float* bm1 = (const float*)d_in[9];
    const float* Wm2 = (const float*)d_in[10];
    const float* bm2 = (const float*)d_in[11];
    float* out = (float*)d_out;

    int N = in_sizes[0] / 64;
    int E = in_sizes[1];

    // workspace layout
    float* ws = (float*)d_ws;
    float* dinv = ws;                        // [N]
    float* B1 = ws + N;                      // [N,64] X1
    float* B2 = B1 + (size_t)N * 64;         // [N,64] X2
    float* B3 = B2 + (size_t)N * 64;         // [N,64] H2
    float* B4 = B3 + (size_t)N * 64;         // [N,64] H1
    int* row_ptr = (int*)(B4 + (size_t)N * 64);  // [N+1]
    int* cursor = row_ptr + (N + 1);             // [N] (counts, then cursors)
    int* col = cursor + N;                       // [E]
    int* bsum = col + E;                         // [<=1024]

    int eblk = (E + 255) / 256;
    int nblk = (N + 255) / 256;  // == #blocks for blocksum/scanfinal (391)
    int pblk = (N * 64 + 255) / 256;  // prop: 1 wave/node, 4 waves/block

    // ---- CSR build (counts in `cursor`) ----
    hipMemsetAsync(cursor, 0, (size_t)N * sizeof(int), stream);
    k_hist<<<eblk, 256, 0, stream>>>(dst, cursor, E);
    k_blocksum<<<nblk, 256, 0, stream>>>(cursor, bsum, N);
    k_scanbsum<<<1, 1024, 0, stream>>>(bsum, nblk);
    k_scanfinal<<<nblk, 256, 0, stream>>>(cursor, bsum, row_ptr, cursor, dinv, N, E);
    k_place<<<eblk, 256, 0, stream>>>(src, dst, cursor, col, E);

    // ---- layer 1 (X0 = features) ----
    k_prop<1><<<pblk, 256, 0, stream>>>(features, row_ptr, col, dinv, nullptr, B1, N);
    k_prop<2><<<pblk, 256, 0, stream>>>(B1, row_ptr, col, dinv, features, B2, N);
    k_cheb_lin<<<2048, 256, 0, stream>>>(features, B1, B2, W1, b1, B4, N);

    // ---- layer 2 (X0 = H1 = B4) ----
    k_prop<1><<<pblk, 256, 0, stream>>>(B4, row_ptr, col, dinv, nullptr, B1, N);
    k_prop<2><<<pblk, 256, 0, stream>>>(B1, row_ptr, col, dinv, B4, B2, N);
    k_cheb_lin<<<2048, 256, 0, stream>>>(B4, B1, B2, W2, b2, B3, N);

    // ---- MLP head ----
    k_mlp<<<2048, 256, 0, stream>>>(B3, Wm1, bm1, Wm2, bm2, out, N);
}

// Round 3
// 639.932 us; speedup vs baseline: 2.2380x; 1.3814x over previous
//
#include <hip/hip_runtime.h>

// ChebNet fp32, round 3: tiled register-blocked GEMMs for dense layers.
// CSR-gather prop unchanged from R2.

// ---------- CSR build ----------

__global__ void k_hist(const int* __restrict__ dst, int* __restrict__ cnt, int E) {
    int e = blockIdx.x * blockDim.x + threadIdx.x;
    if (e < E) atomicAdd(&cnt[dst[e]], 1);
}

__global__ void k_blocksum(const int* __restrict__ cnt, int* __restrict__ bsum, int N) {
    __shared__ int red[256];
    int i = blockIdx.x * 256 + threadIdx.x;
    red[threadIdx.x] = (i < N) ? cnt[i] : 0;
    __syncthreads();
    for (int s = 128; s > 0; s >>= 1) {
        if (threadIdx.x < s) red[threadIdx.x] += red[threadIdx.x + s];
        __syncthreads();
    }
    if (threadIdx.x == 0) bsum[blockIdx.x] = red[0];
}

__global__ void k_scanbsum(int* bsum, int nb) {
    __shared__ int sh[1024];
    int tid = threadIdx.x;
    int v = (tid < nb) ? bsum[tid] : 0;
    sh[tid] = v;
    __syncthreads();
    for (int off = 1; off < 1024; off <<= 1) {
        int t = 0;
        if (tid >= off) t = sh[tid - off];
        __syncthreads();
        sh[tid] += t;
        __syncthreads();
    }
    if (tid < nb) bsum[tid] = sh[tid] - v;
}

__global__ void k_scanfinal(const int* __restrict__ cnt, const int* __restrict__ bsum,
                            int* __restrict__ row_ptr, int* __restrict__ cursor,
                            float* __restrict__ dinv, int N, int E) {
    __shared__ int sh[256];
    int i = blockIdx.x * 256 + threadIdx.x;
    int v = (i < N) ? cnt[i] : 0;
    sh[threadIdx.x] = v;
    __syncthreads();
    for (int off = 1; off < 256; off <<= 1) {
        int t = 0;
        if (threadIdx.x >= off) t = sh[threadIdx.x - off];
        __syncthreads();
        sh[threadIdx.x] += t;
        __syncthreads();
    }
    int excl = sh[threadIdx.x] - v + bsum[blockIdx.x];
    if (i < N) {
        row_ptr[i] = excl;
        cursor[i] = excl;
        dinv[i] = rsqrtf(fmaxf((float)v, 1.0f));
    }
    if (blockIdx.x == 0 && threadIdx.x == 0) row_ptr[N] = E;
}

__global__ void k_place(const int* __restrict__ src, const int* __restrict__ dst,
                        int* __restrict__ cursor, int* __restrict__ col, int E) {
    int e = blockIdx.x * blockDim.x + threadIdx.x;
    if (e < E) {
        int p = atomicAdd(&cursor[dst[e]], 1);
        col[p] = src[e];
    }
}

// ---------- propagation (gather) ----------
template <int MODE>
__global__ __launch_bounds__(256) void k_prop(
    const float* __restrict__ X, const int* __restrict__ rp,
    const int* __restrict__ col, const float* __restrict__ dinv,
    const float* __restrict__ X0, float* __restrict__ OUT, int N) {
    int wid = (blockIdx.x * blockDim.x + threadIdx.x) >> 6;
    int lane = threadIdx.x & 63;
    if (wid >= N) return;
    int beg = rp[wid], end = rp[wid + 1];
    float acc0 = 0.0f, acc1 = 0.0f;
    int e = beg;
    for (; e + 1 < end; e += 2) {
        int s0 = col[e], s1 = col[e + 1];
        float d0 = dinv[s0], d1 = dinv[s1];
        float x0 = X[(size_t)s0 * 64 + lane];
        float x1 = X[(size_t)s1 * 64 + lane];
        acc0 = fmaf(x0, d0, acc0);
        acc1 = fmaf(x1, d1, acc1);
    }
    if (e < end) {
        int s0 = col[e];
        acc0 = fmaf(X[(size_t)s0 * 64 + lane], dinv[s0], acc0);
    }
    float acc = acc0 + acc1;
    float di = dinv[wid];
    if (MODE == 1) {
        OUT[(size_t)wid * 64 + lane] = -di * acc;
    } else {
        OUT[(size_t)wid * 64 + lane] = fmaf(-2.0f * di, acc, -X0[(size_t)wid * 64 + lane]);
    }
}

// ---------- cheb linear: Y[N,64] = relu([X0|X1|X2] @ W[192,64] + b) ----------
// 64-node tile, 256 threads = 16 col-groups x 16 row-groups, 4x4 micro-tile.
__global__ __launch_bounds__(256) void k_cheb_gemm(
    const float* __restrict__ X0, const float* __restrict__ X1,
    const float* __restrict__ X2, const float* __restrict__ W,
    const float* __restrict__ b, float* __restrict__ Y, int N) {
    __shared__ float Ws[192][64];   // 48 KB, row-major like W
    __shared__ float Xs[64][65];    // node-major, +1 pad
    __shared__ float bs[64];
    int t = threadIdx.x;
    for (int i = t; i < 192 * 64; i += 256) Ws[i >> 6][i & 63] = W[i];
    if (t < 64) bs[t] = b[t];

    int c4 = (t & 15) * 4;   // output col base
    int r4 = (t >> 4) * 4;   // row (node) base within tile
    int node0 = blockIdx.x * 64;
    float acc[4][4] = {{0}};

    const float* Xp[3] = {X0, X1, X2};
#pragma unroll 1
    for (int chunk = 0; chunk < 3; chunk++) {
        const float* X = Xp[chunk];
        __syncthreads();
        // stage 64x64 tile: thread reads float4, writes 4 scalars (bank-clean)
        {
            int f4 = (t & 15) * 4;
            int nl0 = t >> 4;  // 16 nodes per pass
            for (int p = 0; p < 4; p++) {
                int nl = nl0 + p * 16;
                int node = node0 + nl;
                float4 v = make_float4(0.f, 0.f, 0.f, 0.f);
                if (node < N) v = *(const float4*)&X[(size_t)node * 64 + f4];
                Xs[nl][f4 + 0] = v.x;
                Xs[nl][f4 + 1] = v.y;
                Xs[nl][f4 + 2] = v.z;
                Xs[nl][f4 + 3] = v.w;
            }
        }
        __syncthreads();
        int wrow = chunk * 64;
#pragma unroll 8
        for (int k = 0; k < 64; k++) {
            float4 wv = *(const float4*)&Ws[wrow + k][c4];
            float x0v = Xs[r4 + 0][k];
            float x1v = Xs[r4 + 1][k];
            float x2v = Xs[r4 + 2][k];
            float x3v = Xs[r4 + 3][k];
            acc[0][0] = fmaf(x0v, wv.x, acc[0][0]);
            acc[0][1] = fmaf(x0v, wv.y, acc[0][1]);
            acc[0][2] = fmaf(x0v, wv.z, acc[0][2]);
            acc[0][3] = fmaf(x0v, wv.w, acc[0][3]);
            acc[1][0] = fmaf(x1v, wv.x, acc[1][0]);
            acc[1][1] = fmaf(x1v, wv.y, acc[1][1]);
            acc[1][2] = fmaf(x1v, wv.z, acc[1][2]);
            acc[1][3] = fmaf(x1v, wv.w, acc[1][3]);
            acc[2][0] = fmaf(x2v, wv.x, acc[2][0]);
            acc[2][1] = fmaf(x2v, wv.y, acc[2][1]);
            acc[2][2] = fmaf(x2v, wv.z, acc[2][2]);
            acc[2][3] = fmaf(x2v, wv.w, acc[2][3]);
            acc[3][0] = fmaf(x3v, wv.x, acc[3][0]);
            acc[3][1] = fmaf(x3v, wv.y, acc[3][1]);
            acc[3][2] = fmaf(x3v, wv.z, acc[3][2]);
            acc[3][3] = fmaf(x3v, wv.w, acc[3][3]);
        }
    }
    // epilogue: bias + relu + store
#pragma unroll
    for (int i = 0; i < 4; i++) {
        int row = node0 + r4 + i;
        if (row < N) {
            float4 o;
            o.x = fmaxf(acc[i][0] + bs[c4 + 0], 0.0f);
            o.y = fmaxf(acc[i][1] + bs[c4 + 1], 0.0f);
            o.z = fmaxf(acc[i][2] + bs[c4 + 2], 0.0f);
            o.w = fmaxf(acc[i][3] + bs[c4 + 3], 0.0f);
            *(float4*)&Y[(size_t)row * 64 + c4] = o;
        }
    }
}

// ---------- MLP head: out = relu(H@Wm1+bm1) @ Wm2 + bm2 ----------
__global__ __launch_bounds__(256) void k_mlp_gemm(
    const float* __restrict__ H, const float* __restrict__ Wm1,
    const float* __restrict__ bm1, const float* __restrict__ Wm2,
    const float* __restrict__ bm2, float* __restrict__ out, int N) {
    __shared__ float W1s[64][64];   // 16 KB
    __shared__ float W2s[64][32];   // 8 KB
    __shared__ float Hs[64][65];    // input tile
    __shared__ float Hid[64][65];   // hidden tile
    __shared__ float b1s[64];
    __shared__ float b2s[32];
    int t = threadIdx.x;
    for (int i = t; i < 64 * 64; i += 256) W1s[i >> 6][i & 63] = Wm1[i];
    for (int i = t; i < 64 * 32; i += 256) W2s[i >> 5][i & 31] = Wm2[i];
    if (t < 64) b1s[t] = bm1[t];
    else if (t < 96) b2s[t - 64] = bm2[t - 64];

    int node0 = blockIdx.x * 64;
    // stage H tile
    {
        int f4 = (t & 15) * 4;
        int nl0 = t >> 4;
        for (int p = 0; p < 4; p++) {
            int nl = nl0 + p * 16;
            int node = node0 + nl;
            float4 v = make_float4(0.f, 0.f, 0.f, 0.f);
            if (node < N) v = *(const float4*)&H[(size_t)node * 64 + f4];
            Hs[nl][f4 + 0] = v.x;
            Hs[nl][f4 + 1] = v.y;
            Hs[nl][f4 + 2] = v.z;
            Hs[nl][f4 + 3] = v.w;
        }
    }
    __syncthreads();

    // GEMM1: hidden = relu(Hs @ W1 + b1), 4x4 micro-tile per thread
    {
        int c4 = (t & 15) * 4;
        int r4 = (t >> 4) * 4;
        float acc[4][4] = {{0}};
#pragma unroll 8
        for (int k = 0; k < 64; k++) {
            float4 wv = *(const float4*)&W1s[k][c4];
            float x0v = Hs[r4 + 0][k];
            float x1v = Hs[r4 + 1][k];
            float x2v = Hs[r4 + 2][k];
            float x3v = Hs[r4 + 3][k];
            acc[0][0] = fmaf(x0v, wv.x, acc[0][0]);
            acc[0][1] = fmaf(x0v, wv.y, acc[0][1]);
            acc[0][2] = fmaf(x0v, wv.z, acc[0][2]);
            acc[0][3] = fmaf(x0v, wv.w, acc[0][3]);
            acc[1][0] = fmaf(x1v, wv.x, acc[1][0]);
            acc[1][1] = fmaf(x1v, wv.y, acc[1][1]);
            acc[1][2] = fmaf(x1v, wv.z, acc[1][2]);
            acc[1][3] = fmaf(x1v, wv.w, acc[1][3]);
            acc[2][0] = fmaf(x2v, wv.x, acc[2][0]);
            acc[2][1] = fmaf(x2v, wv.y, acc[2][1]);
            acc[2][2] = fmaf(x2v, wv.z, acc[2][2]);
            acc[2][3] = fmaf(x2v, wv.w, acc[2][3]);
            acc[3][0] = fmaf(x3v, wv.x, acc[3][0]);
            acc[3][1] = fmaf(x3v, wv.y, acc[3][1]);
            acc[3][2] = fmaf(x3v, wv.z, acc[3][2]);
            acc[3][3] = fmaf(x3v, wv.w, acc[3][3]);
        }
        __syncthreads();  // Hs no longer needed
#pragma unroll
        for (int i = 0; i < 4; i++)
#pragma unroll
            for (int j = 0; j < 4; j++)
                Hid[r4 + i][c4 + j] = fmaxf(acc[i][j] + b1s[c4 + j], 0.0f);
    }
    __syncthreads();

    // GEMM2: out = Hid @ W2 + b2; thread = 2 rows x 4 cols
    {
        int c4 = (t & 7) * 4;
        int r2 = (t >> 3) * 2;
        float acc[2][4] = {{0}};
#pragma unroll 8
        for (int k = 0; k < 64; k++) {
            float4 wv = *(const float4*)&W2s[k][c4];
            float h0 = Hid[r2 + 0][k];
            float h1 = Hid[r2 + 1][k];
            acc[0][0] = fmaf(h0, wv.x, acc[0][0]);
            acc[0][1] = fmaf(h0, wv.y, acc[0][1]);
            acc[0][2] = fmaf(h0, wv.z, acc[0][2]);
            acc[0][3] = fmaf(h0, wv.w, acc[0][3]);
            acc[1][0] = fmaf(h1, wv.x, acc[1][0]);
            acc[1][1] = fmaf(h1, wv.y, acc[1][1]);
            acc[1][2] = fmaf(h1, wv.z, acc[1][2]);
            acc[1][3] = fmaf(h1, wv.w, acc[1][3]);
        }
#pragma unroll
        for (int i = 0; i < 2; i++) {
            int row = node0 + r2 + i;
            if (row < N) {
                float4 o;
                o.x = acc[i][0] + b2s[c4 + 0];
                o.y = acc[i][1] + b2s[c4 + 1];
                o.z = acc[i][2] + b2s[c4 + 2];
                o.w = acc[i][3] + b2s[c4 + 3];
                *(float4*)&out[(size_t)row * 32 + c4] = o;
            }
        }
    }
}

extern "C" void kernel_launch(void* const* d_in, const int* in_sizes, int n_in,
                              void* d_out, int out_size, void* d_ws, size_t ws_size,
                              hipStream_t stream) {
    const float* features = (const float*)d_in[0];
    const int* src = (const int*)d_in[1];
    const int* dst = (const int*)d_in[2];
    const float* W1 = (const float*)d_in[4];
    const float* b1 = (const float*)d_in[5];
    const float* W2 = (const float*)d_in[6];
    const float* b2 = (const float*)d_in[7];
    const float* Wm1 = (const float*)d_in[8];
    const float* bm1 = (const float*)d_in[9];
    const float* Wm2 = (const float*)d_in[10];
    const float* bm2 = (const float*)d_in[11];
    float* out = (float*)d_out;

    int N = in_sizes[0] / 64;
    int E = in_sizes[1];

    float* ws = (float*)d_ws;
    float* dinv = ws;                        // [N]
    float* B1 = ws + N;                      // [N,64] X1
    float* B2 = B1 + (size_t)N * 64;         // [N,64] X2
    float* B3 = B2 + (size_t)N * 64;         // [N,64] H2
    float* B4 = B3 + (size_t)N * 64;         // [N,64] H1
    int* row_ptr = (int*)(B4 + (size_t)N * 64);
    int* cursor = row_ptr + (N + 1);
    int* col = cursor + N;
    int* bsum = col + E;

    int eblk = (E + 255) / 256;
    int nblk = (N + 255) / 256;
    int pblk = (N * 64 + 255) / 256;
    int gblk = (N + 63) / 64;

    // CSR build
    hipMemsetAsync(cursor, 0, (size_t)N * sizeof(int), stream);
    k_hist<<<eblk, 256, 0, stream>>>(dst, cursor, E);
    k_blocksum<<<nblk, 256, 0, stream>>>(cursor, bsum, N);
    k_scanbsum<<<1, 1024, 0, stream>>>(bsum, nblk);
    k_scanfinal<<<nblk, 256, 0, stream>>>(cursor, bsum, row_ptr, cursor, dinv, N, E);
    k_place<<<eblk, 256, 0, stream>>>(src, dst, cursor, col, E);

    // layer 1
    k_prop<1><<<pblk, 256, 0, stream>>>(features, row_ptr, col, dinv, nullptr, B1, N);
    k_prop<2><<<pblk, 256, 0, stream>>>(B1, row_ptr, col, dinv, features, B2, N);
    k_cheb_gemm<<<gblk, 256, 0, stream>>>(features, B1, B2, W1, b1, B4, N);

    // layer 2
    k_prop<1><<<pblk, 256, 0, stream>>>(B4, row_ptr, col, dinv, nullptr, B1, N);
    k_prop<2><<<pblk, 256, 0, stream>>>(B1, row_ptr, col, dinv, B4, B2, N);
    k_cheb_gemm<<<gblk, 256, 0, stream>>>(B4, B1, B2, W2, b2, B3, N);

    // MLP head
    k_mlp_gemm<<<gblk, 256, 0, stream>>>(B3, Wm1, bm1, Wm2, bm2, out, N);
}

// Round 4
// 534.643 us; speedup vs baseline: 2.6787x; 1.1969x over previous
//
#include <hip/hip_runtime.h>

// ChebNet fp32, round 4: wide-gather prop (float4 x 4 edge-groups per wave),
// packed (src,dinv) edge array. Dense GEMMs unchanged from R3.

// ---------- CSR build ----------

__global__ void k_hist(const int* __restrict__ dst, int* __restrict__ cnt, int E) {
    int e = blockIdx.x * blockDim.x + threadIdx.x;
    if (e < E) atomicAdd(&cnt[dst[e]], 1);
}

__global__ void k_blocksum(const int* __restrict__ cnt, int* __restrict__ bsum, int N) {
    __shared__ int red[256];
    int i = blockIdx.x * 256 + threadIdx.x;
    red[threadIdx.x] = (i < N) ? cnt[i] : 0;
    __syncthreads();
    for (int s = 128; s > 0; s >>= 1) {
        if (threadIdx.x < s) red[threadIdx.x] += red[threadIdx.x + s];
        __syncthreads();
    }
    if (threadIdx.x == 0) bsum[blockIdx.x] = red[0];
}

__global__ void k_scanbsum(int* bsum, int nb) {
    __shared__ int sh[1024];
    int tid = threadIdx.x;
    int v = (tid < nb) ? bsum[tid] : 0;
    sh[tid] = v;
    __syncthreads();
    for (int off = 1; off < 1024; off <<= 1) {
        int t = 0;
        if (tid >= off) t = sh[tid - off];
        __syncthreads();
        sh[tid] += t;
        __syncthreads();
    }
    if (tid < nb) bsum[tid] = sh[tid] - v;
}

__global__ void k_scanfinal(const int* __restrict__ cnt, const int* __restrict__ bsum,
                            int* __restrict__ row_ptr, int* __restrict__ cursor,
                            float* __restrict__ dinv, int N, int E) {
    __shared__ int sh[256];
    int i = blockIdx.x * 256 + threadIdx.x;
    int v = (i < N) ? cnt[i] : 0;
    sh[threadIdx.x] = v;
    __syncthreads();
    for (int off = 1; off < 256; off <<= 1) {
        int t = 0;
        if (threadIdx.x >= off) t = sh[threadIdx.x - off];
        __syncthreads();
        sh[threadIdx.x] += t;
        __syncthreads();
    }
    int excl = sh[threadIdx.x] - v + bsum[blockIdx.x];
    if (i < N) {
        row_ptr[i] = excl;
        cursor[i] = excl;
        dinv[i] = rsqrtf(fmaxf((float)v, 1.0f));
    }
    if (blockIdx.x == 0 && threadIdx.x == 0) row_ptr[N] = E;
}

// place packed (src, dinv[src]) pairs
__global__ void k_place(const int* __restrict__ src, const int* __restrict__ dst,
                        const float* __restrict__ dinv,
                        int* __restrict__ cursor, int2* __restrict__ cw, int E) {
    int e = blockIdx.x * blockDim.x + threadIdx.x;
    if (e < E) {
        int s = src[e];
        int p = atomicAdd(&cursor[dst[e]], 1);
        cw[p] = make_int2(s, __float_as_int(dinv[s]));
    }
}

// ---------- propagation (wide gather) ----------
// wave = dst node. 4 lane-groups of 16; group g takes edges beg+g, beg+g+4,...
// lane loads float4 of the source row. Butterfly-reduce across groups.
// MODE 1: OUT = -dinv[i]*sum ;  MODE 2: OUT = -2*dinv[i]*sum - X0[i]
template <int MODE>
__global__ __launch_bounds__(256) void k_prop(
    const float* __restrict__ X, const int* __restrict__ rp,
    const int2* __restrict__ cw, const float* __restrict__ dinv,
    const float* __restrict__ X0, float* __restrict__ OUT, int N) {
    int wid = (blockIdx.x * blockDim.x + threadIdx.x) >> 6;
    int lane = threadIdx.x & 63;
    if (wid >= N) return;
    int g = lane >> 4;        // edge-subgroup 0..3
    int fl = (lane & 15) * 4; // feature base
    int beg = rp[wid], end = rp[wid + 1];
    float4 acc = make_float4(0.f, 0.f, 0.f, 0.f);
    for (int e = beg + g; e < end; e += 4) {
        int2 c = cw[e];
        float w = __int_as_float(c.y);
        float4 v = *(const float4*)&X[(size_t)c.x * 64 + fl];
        acc.x = fmaf(v.x, w, acc.x);
        acc.y = fmaf(v.y, w, acc.y);
        acc.z = fmaf(v.z, w, acc.z);
        acc.w = fmaf(v.w, w, acc.w);
    }
    // butterfly across the 4 groups (lanes fl equal mod 16 hold same features)
    acc.x += __shfl_xor(acc.x, 16);
    acc.y += __shfl_xor(acc.y, 16);
    acc.z += __shfl_xor(acc.z, 16);
    acc.w += __shfl_xor(acc.w, 16);
    acc.x += __shfl_xor(acc.x, 32);
    acc.y += __shfl_xor(acc.y, 32);
    acc.z += __shfl_xor(acc.z, 32);
    acc.w += __shfl_xor(acc.w, 32);
    if (g == 0) {
        float di = dinv[wid];
        float4 o;
        if (MODE == 1) {
            o.x = -di * acc.x; o.y = -di * acc.y; o.z = -di * acc.z; o.w = -di * acc.w;
        } else {
            float4 x0 = *(const float4*)&X0[(size_t)wid * 64 + fl];
            float m = -2.0f * di;
            o.x = fmaf(m, acc.x, -x0.x);
            o.y = fmaf(m, acc.y, -x0.y);
            o.z = fmaf(m, acc.z, -x0.z);
            o.w = fmaf(m, acc.w, -x0.w);
        }
        *(float4*)&OUT[(size_t)wid * 64 + fl] = o;
    }
}

// ---------- cheb linear: Y[N,64] = relu([X0|X1|X2] @ W[192,64] + b) ----------
__global__ __launch_bounds__(256) void k_cheb_gemm(
    const float* __restrict__ X0, const float* __restrict__ X1,
    const float* __restrict__ X2, const float* __restrict__ W,
    const float* __restrict__ b, float* __restrict__ Y, int N) {
    __shared__ float Ws[192][64];
    __shared__ float Xs[64][65];
    __shared__ float bs[64];
    int t = threadIdx.x;
    for (int i = t; i < 192 * 64; i += 256) Ws[i >> 6][i & 63] = W[i];
    if (t < 64) bs[t] = b[t];

    int c4 = (t & 15) * 4;
    int r4 = (t >> 4) * 4;
    int node0 = blockIdx.x * 64;
    float acc[4][4] = {{0}};

    const float* Xp[3] = {X0, X1, X2};
#pragma unroll 1
    for (int chunk = 0; chunk < 3; chunk++) {
        const float* X = Xp[chunk];
        __syncthreads();
        {
            int f4 = (t & 15) * 4;
            int nl0 = t >> 4;
            for (int p = 0; p < 4; p++) {
                int nl = nl0 + p * 16;
                int node = node0 + nl;
                float4 v = make_float4(0.f, 0.f, 0.f, 0.f);
                if (node < N) v = *(const float4*)&X[(size_t)node * 64 + f4];
                Xs[nl][f4 + 0] = v.x;
                Xs[nl][f4 + 1] = v.y;
                Xs[nl][f4 + 2] = v.z;
                Xs[nl][f4 + 3] = v.w;
            }
        }
        __syncthreads();
        int wrow = chunk * 64;
#pragma unroll 8
        for (int k = 0; k < 64; k++) {
            float4 wv = *(const float4*)&Ws[wrow + k][c4];
            float x0v = Xs[r4 + 0][k];
            float x1v = Xs[r4 + 1][k];
            float x2v = Xs[r4 + 2][k];
            float x3v = Xs[r4 + 3][k];
            acc[0][0] = fmaf(x0v, wv.x, acc[0][0]);
            acc[0][1] = fmaf(x0v, wv.y, acc[0][1]);
            acc[0][2] = fmaf(x0v, wv.z, acc[0][2]);
            acc[0][3] = fmaf(x0v, wv.w, acc[0][3]);
            acc[1][0] = fmaf(x1v, wv.x, acc[1][0]);
            acc[1][1] = fmaf(x1v, wv.y, acc[1][1]);
            acc[1][2] = fmaf(x1v, wv.z, acc[1][2]);
            acc[1][3] = fmaf(x1v, wv.w, acc[1][3]);
            acc[2][0] = fmaf(x2v, wv.x, acc[2][0]);
            acc[2][1] = fmaf(x2v, wv.y, acc[2][1]);
            acc[2][2] = fmaf(x2v, wv.z, acc[2][2]);
            acc[2][3] = fmaf(x2v, wv.w, acc[2][3]);
            acc[3][0] = fmaf(x3v, wv.x, acc[3][0]);
            acc[3][1] = fmaf(x3v, wv.y, acc[3][1]);
            acc[3][2] = fmaf(x3v, wv.z, acc[3][2]);
            acc[3][3] = fmaf(x3v, wv.w, acc[3][3]);
        }
    }
#pragma unroll
    for (int i = 0; i < 4; i++) {
        int row = node0 + r4 + i;
        if (row < N) {
            float4 o;
            o.x = fmaxf(acc[i][0] + bs[c4 + 0], 0.0f);
            o.y = fmaxf(acc[i][1] + bs[c4 + 1], 0.0f);
            o.z = fmaxf(acc[i][2] + bs[c4 + 2], 0.0f);
            o.w = fmaxf(acc[i][3] + bs[c4 + 3], 0.0f);
            *(float4*)&Y[(size_t)row * 64 + c4] = o;
        }
    }
}

// ---------- MLP head ----------
__global__ __launch_bounds__(256) void k_mlp_gemm(
    const float* __restrict__ H, const float* __restrict__ Wm1,
    const float* __restrict__ bm1, const float* __restrict__ Wm2,
    const float* __restrict__ bm2, float* __restrict__ out, int N) {
    __shared__ float W1s[64][64];
    __shared__ float W2s[64][32];
    __shared__ float Hs[64][65];
    __shared__ float Hid[64][65];
    __shared__ float b1s[64];
    __shared__ float b2s[32];
    int t = threadIdx.x;
    for (int i = t; i < 64 * 64; i += 256) W1s[i >> 6][i & 63] = Wm1[i];
    for (int i = t; i < 64 * 32; i += 256) W2s[i >> 5][i & 31] = Wm2[i];
    if (t < 64) b1s[t] = bm1[t];
    else if (t < 96) b2s[t - 64] = bm2[t - 64];

    int node0 = blockIdx.x * 64;
    {
        int f4 = (t & 15) * 4;
        int nl0 = t >> 4;
        for (int p = 0; p < 4; p++) {
            int nl = nl0 + p * 16;
            int node = node0 + nl;
            float4 v = make_float4(0.f, 0.f, 0.f, 0.f);
            if (node < N) v = *(const float4*)&H[(size_t)node * 64 + f4];
            Hs[nl][f4 + 0] = v.x;
            Hs[nl][f4 + 1] = v.y;
            Hs[nl][f4 + 2] = v.z;
            Hs[nl][f4 + 3] = v.w;
        }
    }
    __syncthreads();
    {
        int c4 = (t & 15) * 4;
        int r4 = (t >> 4) * 4;
        float acc[4][4] = {{0}};
#pragma unroll 8
        for (int k = 0; k < 64; k++) {
            float4 wv = *(const float4*)&W1s[k][c4];
            float x0v = Hs[r4 + 0][k];
            float x1v = Hs[r4 + 1][k];
            float x2v = Hs[r4 + 2][k];
            float x3v = Hs[r4 + 3][k];
            acc[0][0] = fmaf(x0v, wv.x, acc[0][0]);
            acc[0][1] = fmaf(x0v, wv.y, acc[0][1]);
            acc[0][2] = fmaf(x0v, wv.z, acc[0][2]);
            acc[0][3] = fmaf(x0v, wv.w, acc[0][3]);
            acc[1][0] = fmaf(x1v, wv.x, acc[1][0]);
            acc[1][1] = fmaf(x1v, wv.y, acc[1][1]);
            acc[1][2] = fmaf(x1v, wv.z, acc[1][2]);
            acc[1][3] = fmaf(x1v, wv.w, acc[1][3]);
            acc[2][0] = fmaf(x2v, wv.x, acc[2][0]);
            acc[2][1] = fmaf(x2v, wv.y, acc[2][1]);
            acc[2][2] = fmaf(x2v, wv.z, acc[2][2]);
            acc[2][3] = fmaf(x2v, wv.w, acc[2][3]);
            acc[3][0] = fmaf(x3v, wv.x, acc[3][0]);
            acc[3][1] = fmaf(x3v, wv.y, acc[3][1]);
            acc[3][2] = fmaf(x3v, wv.z, acc[3][2]);
            acc[3][3] = fmaf(x3v, wv.w, acc[3][3]);
        }
        __syncthreads();
#pragma unroll
        for (int i = 0; i < 4; i++)
#pragma unroll
            for (int j = 0; j < 4; j++)
                Hid[r4 + i][c4 + j] = fmaxf(acc[i][j] + b1s[c4 + j], 0.0f);
    }
    __syncthreads();
    {
        int c4 = (t & 7) * 4;
        int r2 = (t >> 3) * 2;
        float acc[2][4] = {{0}};
#pragma unroll 8
        for (int k = 0; k < 64; k++) {
            float4 wv = *(const float4*)&W2s[k][c4];
            float h0 = Hid[r2 + 0][k];
            float h1 = Hid[r2 + 1][k];
            acc[0][0] = fmaf(h0, wv.x, acc[0][0]);
            acc[0][1] = fmaf(h0, wv.y, acc[0][1]);
            acc[0][2] = fmaf(h0, wv.z, acc[0][2]);
            acc[0][3] = fmaf(h0, wv.w, acc[0][3]);
            acc[1][0] = fmaf(h1, wv.x, acc[1][0]);
            acc[1][1] = fmaf(h1, wv.y, acc[1][1]);
            acc[1][2] = fmaf(h1, wv.z, acc[1][2]);
            acc[1][3] = fmaf(h1, wv.w, acc[1][3]);
        }
#pragma unroll
        for (int i = 0; i < 2; i++) {
            int row = node0 + r2 + i;
            if (row < N) {
                float4 o;
                o.x = acc[i][0] + b2s[c4 + 0];
                o.y = acc[i][1] + b2s[c4 + 1];
                o.z = acc[i][2] + b2s[c4 + 2];
                o.w = acc[i][3] + b2s[c4 + 3];
                *(float4*)&out[(size_t)row * 32 + c4] = o;
            }
        }
    }
}

extern "C" void kernel_launch(void* const* d_in, const int* in_sizes, int n_in,
                              void* d_out, int out_size, void* d_ws, size_t ws_size,
                              hipStream_t stream) {
    const float* features = (const float*)d_in[0];
    const int* src = (const int*)d_in[1];
    const int* dst = (const int*)d_in[2];
    const float* W1 = (const float*)d_in[4];
    const float* b1 = (const float*)d_in[5];
    const float* W2 = (const float*)d_in[6];
    const float* b2 = (const float*)d_in[7];
    const float* Wm1 = (const float*)d_in[8];
    const float* bm1 = (const float*)d_in[9];
    const float* Wm2 = (const float*)d_in[10];
    const float* bm2 = (const float*)d_in[11];
    float* out = (float*)d_out;

    int N = in_sizes[0] / 64;
    int E = in_sizes[1];

    float* ws = (float*)d_ws;
    float* dinv = ws;                        // [N]
    float* B1 = ws + N;                      // [N,64] X1
    float* B2 = B1 + (size_t)N * 64;         // [N,64] X2
    float* B3 = B2 + (size_t)N * 64;         // [N,64] H2
    float* B4 = B3 + (size_t)N * 64;         // [N,64] H1
    int* row_ptr = (int*)(B4 + (size_t)N * 64);       // [N+1]
    int* cursor = row_ptr + (N + 1);                  // [N]
    int* bsum = cursor + N;                           // [<=1024]
    // 8-byte aligned edge array
    int2* cw = (int2*)(((uintptr_t)(bsum + 1024) + 7) & ~(uintptr_t)7);  // [E]

    int eblk = (E + 255) / 256;
    int nblk = (N + 255) / 256;
    int pblk = (N * 64 + 255) / 256;
    int gblk = (N + 63) / 64;

    // CSR build
    hipMemsetAsync(cursor, 0, (size_t)N * sizeof(int), stream);
    k_hist<<<eblk, 256, 0, stream>>>(dst, cursor, E);
    k_blocksum<<<nblk, 256, 0, stream>>>(cursor, bsum, N);
    k_scanbsum<<<1, 1024, 0, stream>>>(bsum, nblk);
    k_scanfinal<<<nblk, 256, 0, stream>>>(cursor, bsum, row_ptr, cursor, dinv, N, E);
    k_place<<<eblk, 256, 0, stream>>>(src, dst, dinv, cursor, cw, E);

    // layer 1
    k_prop<1><<<pblk, 256, 0, stream>>>(features, row_ptr, cw, dinv, nullptr, B1, N);
    k_prop<2><<<pblk, 256, 0, stream>>>(B1, row_ptr, cw, dinv, features, B2, N);
    k_cheb_gemm<<<gblk, 256, 0, stream>>>(features, B1, B2, W1, b1, B4, N);

    // layer 2
    k_prop<1><<<pblk, 256, 0, stream>>>(B4, row_ptr, cw, dinv, nullptr, B1, N);
    k_prop<2><<<pblk, 256, 0, stream>>>(B1, row_ptr, cw, dinv, B4, B2, N);
    k_cheb_gemm<<<gblk, 256, 0, stream>>>(B4, B1, B2, W2, b2, B3, N);

    // MLP head
    k_mlp_gemm<<<gblk, 256, 0, stream>>>(B3, Wm1, bm1, Wm2, bm2, out, N);
}

// Round 5
// 495.157 us; speedup vs baseline: 2.8923x; 1.0797x over previous
//
#include <hip/hip_runtime.h>

// ChebNet fp32, round 5: float4-along-k GEMMs, chunked W staging (4 blocks/CU),
// conflict-free LDS. Prop/CSR unchanged from R4.

// ---------- CSR build ----------

__global__ void k_hist(const int* __restrict__ dst, int* __restrict__ cnt, int E) {
    int e = blockIdx.x * blockDim.x + threadIdx.x;
    if (e < E) atomicAdd(&cnt[dst[e]], 1);
}

__global__ void k_blocksum(const int* __restrict__ cnt, int* __restrict__ bsum, int N) {
    __shared__ int red[256];
    int i = blockIdx.x * 256 + threadIdx.x;
    red[threadIdx.x] = (i < N) ? cnt[i] : 0;
    __syncthreads();
    for (int s = 128; s > 0; s >>= 1) {
        if (threadIdx.x < s) red[threadIdx.x] += red[threadIdx.x + s];
        __syncthreads();
    }
    if (threadIdx.x == 0) bsum[blockIdx.x] = red[0];
}

__global__ void k_scanbsum(int* bsum, int nb) {
    __shared__ int sh[1024];
    int tid = threadIdx.x;
    int v = (tid < nb) ? bsum[tid] : 0;
    sh[tid] = v;
    __syncthreads();
    for (int off = 1; off < 1024; off <<= 1) {
        int t = 0;
        if (tid >= off) t = sh[tid - off];
        __syncthreads();
        sh[tid] += t;
        __syncthreads();
    }
    if (tid < nb) bsum[tid] = sh[tid] - v;
}

__global__ void k_scanfinal(const int* __restrict__ cnt, const int* __restrict__ bsum,
                            int* __restrict__ row_ptr, int* __restrict__ cursor,
                            float* __restrict__ dinv, int N, int E) {
    __shared__ int sh[256];
    int i = blockIdx.x * 256 + threadIdx.x;
    int v = (i < N) ? cnt[i] : 0;
    sh[threadIdx.x] = v;
    __syncthreads();
    for (int off = 1; off < 256; off <<= 1) {
        int t = 0;
        if (threadIdx.x >= off) t = sh[threadIdx.x - off];
        __syncthreads();
        sh[threadIdx.x] += t;
        __syncthreads();
    }
    int excl = sh[threadIdx.x] - v + bsum[blockIdx.x];
    if (i < N) {
        row_ptr[i] = excl;
        cursor[i] = excl;
        dinv[i] = rsqrtf(fmaxf((float)v, 1.0f));
    }
    if (blockIdx.x == 0 && threadIdx.x == 0) row_ptr[N] = E;
}

__global__ void k_place(const int* __restrict__ src, const int* __restrict__ dst,
                        const float* __restrict__ dinv,
                        int* __restrict__ cursor, int2* __restrict__ cw, int E) {
    int e = blockIdx.x * blockDim.x + threadIdx.x;
    if (e < E) {
        int s = src[e];
        int p = atomicAdd(&cursor[dst[e]], 1);
        cw[p] = make_int2(s, __float_as_int(dinv[s]));
    }
}

// ---------- propagation (wide gather, unchanged) ----------
template <int MODE>
__global__ __launch_bounds__(256) void k_prop(
    const float* __restrict__ X, const int* __restrict__ rp,
    const int2* __restrict__ cw, const float* __restrict__ dinv,
    const float* __restrict__ X0, float* __restrict__ OUT, int N) {
    int wid = (blockIdx.x * blockDim.x + threadIdx.x) >> 6;
    int lane = threadIdx.x & 63;
    if (wid >= N) return;
    int g = lane >> 4;
    int fl = (lane & 15) * 4;
    int beg = rp[wid], end = rp[wid + 1];
    float4 acc = make_float4(0.f, 0.f, 0.f, 0.f);
    for (int e = beg + g; e < end; e += 4) {
        int2 c = cw[e];
        float w = __int_as_float(c.y);
        float4 v = *(const float4*)&X[(size_t)c.x * 64 + fl];
        acc.x = fmaf(v.x, w, acc.x);
        acc.y = fmaf(v.y, w, acc.y);
        acc.z = fmaf(v.z, w, acc.z);
        acc.w = fmaf(v.w, w, acc.w);
    }
    acc.x += __shfl_xor(acc.x, 16);
    acc.y += __shfl_xor(acc.y, 16);
    acc.z += __shfl_xor(acc.z, 16);
    acc.w += __shfl_xor(acc.w, 16);
    acc.x += __shfl_xor(acc.x, 32);
    acc.y += __shfl_xor(acc.y, 32);
    acc.z += __shfl_xor(acc.z, 32);
    acc.w += __shfl_xor(acc.w, 32);
    if (g == 0) {
        float di = dinv[wid];
        float4 o;
        if (MODE == 1) {
            o.x = -di * acc.x; o.y = -di * acc.y; o.z = -di * acc.z; o.w = -di * acc.w;
        } else {
            float4 x0 = *(const float4*)&X0[(size_t)wid * 64 + fl];
            float m = -2.0f * di;
            o.x = fmaf(m, acc.x, -x0.x);
            o.y = fmaf(m, acc.y, -x0.y);
            o.z = fmaf(m, acc.z, -x0.z);
            o.w = fmaf(m, acc.w, -x0.w);
        }
        *(float4*)&OUT[(size_t)wid * 64 + fl] = o;
    }
}

// ---------- cheb linear: Y[N,64] = relu([X0|X1|X2] @ W[192,64] + b) ----------
// 64-node tile. float4-along-k: per k4, thread reads 4 X rows (b128) + 4 W rows
// (b128), does 64 FMAs. W staged one 64x64 chunk at a time -> 34 KB LDS.
__global__ __launch_bounds__(256) void k_cheb_gemm(
    const float* __restrict__ X0, const float* __restrict__ X1,
    const float* __restrict__ X2, const float* __restrict__ W,
    const float* __restrict__ b, float* __restrict__ Y, int N) {
    __shared__ float Ws[64][64];   // current W chunk, 16 KB
    __shared__ float Xs[64][68];   // node-major, pad 4 (16B-aligned rows)
    __shared__ float bs[64];
    int t = threadIdx.x;
    if (t < 64) bs[t] = b[t];

    int c4 = (t & 15) * 4;   // output col base
    int r4 = (t >> 4) * 4;   // node base within tile
    int node0 = blockIdx.x * 64;
    float acc[4][4] = {{0}};

    const float* Xp[3] = {X0, X1, X2};
#pragma unroll 1
    for (int chunk = 0; chunk < 3; chunk++) {
        __syncthreads();  // protect previous chunk's Ws/Xs reads
        // stage W chunk (64x64): 16 float4 per thread
        {
            const float* Wc = W + chunk * 64 * 64;
            for (int i = t; i < 64 * 16; i += 256) {
                int r = i >> 4, c = (i & 15) * 4;
                *(float4*)&Ws[r][c] = *(const float4*)&Wc[r * 64 + c];
            }
        }
        // stage X tile (64 nodes x 64 feats), float4 writes
        {
            const float* X = Xp[chunk];
            int f4 = (t & 15) * 4;
            int nl0 = t >> 4;
            for (int p = 0; p < 4; p++) {
                int nl = nl0 + p * 16;
                int node = node0 + nl;
                float4 v = make_float4(0.f, 0.f, 0.f, 0.f);
                if (node < N) v = *(const float4*)&X[(size_t)node * 64 + f4];
                *(float4*)&Xs[nl][f4] = v;
            }
        }
        __syncthreads();
#pragma unroll 4
        for (int k4 = 0; k4 < 64; k4 += 4) {
            float4 xv[4], wv[4];
#pragma unroll
            for (int i = 0; i < 4; i++) xv[i] = *(const float4*)&Xs[r4 + i][k4];
#pragma unroll
            for (int q = 0; q < 4; q++) wv[q] = *(const float4*)&Ws[k4 + q][c4];
#pragma unroll
            for (int i = 0; i < 4; i++) {
                acc[i][0] = fmaf(xv[i].x, wv[0].x, acc[i][0]);
                acc[i][1] = fmaf(xv[i].x, wv[0].y, acc[i][1]);
                acc[i][2] = fmaf(xv[i].x, wv[0].z, acc[i][2]);
                acc[i][3] = fmaf(xv[i].x, wv[0].w, acc[i][3]);
                acc[i][0] = fmaf(xv[i].y, wv[1].x, acc[i][0]);
                acc[i][1] = fmaf(xv[i].y, wv[1].y, acc[i][1]);
                acc[i][2] = fmaf(xv[i].y, wv[1].z, acc[i][2]);
                acc[i][3] = fmaf(xv[i].y, wv[1].w, acc[i][3]);
                acc[i][0] = fmaf(xv[i].z, wv[2].x, acc[i][0]);
                acc[i][1] = fmaf(xv[i].z, wv[2].y, acc[i][1]);
                acc[i][2] = fmaf(xv[i].z, wv[2].z, acc[i][2]);
                acc[i][3] = fmaf(xv[i].z, wv[2].w, acc[i][3]);
                acc[i][0] = fmaf(xv[i].w, wv[3].x, acc[i][0]);
                acc[i][1] = fmaf(xv[i].w, wv[3].y, acc[i][1]);
                acc[i][2] = fmaf(xv[i].w, wv[3].z, acc[i][2]);
                acc[i][3] = fmaf(xv[i].w, wv[3].w, acc[i][3]);
            }
        }
    }
#pragma unroll
    for (int i = 0; i < 4; i++) {
        int row = node0 + r4 + i;
        if (row < N) {
            float4 o;
            o.x = fmaxf(acc[i][0] + bs[c4 + 0], 0.0f);
            o.y = fmaxf(acc[i][1] + bs[c4 + 1], 0.0f);
            o.z = fmaxf(acc[i][2] + bs[c4 + 2], 0.0f);
            o.w = fmaxf(acc[i][3] + bs[c4 + 3], 0.0f);
            *(float4*)&Y[(size_t)row * 64 + c4] = o;
        }
    }
}

// ---------- MLP head: out = relu(H@Wm1+bm1) @ Wm2 + bm2 ----------
// Hidden tile reuses Hs buffer. 41.8 KB LDS -> 3 blocks/CU.
__global__ __launch_bounds__(256) void k_mlp_gemm(
    const float* __restrict__ H, const float* __restrict__ Wm1,
    const float* __restrict__ bm1, const float* __restrict__ Wm2,
    const float* __restrict__ bm2, float* __restrict__ out, int N) {
    __shared__ float W1s[64][64];
    __shared__ float W2s[64][32];
    __shared__ float Hs[64][68];
    __shared__ float b1s[64];
    __shared__ float b2s[32];
    int t = threadIdx.x;
    for (int i = t; i < 64 * 16; i += 256) {
        int r = i >> 4, c = (i & 15) * 4;
        *(float4*)&W1s[r][c] = *(const float4*)&Wm1[r * 64 + c];
    }
    for (int i = t; i < 64 * 8; i += 256) {
        int r = i >> 3, c = (i & 7) * 4;
        *(float4*)&W2s[r][c] = *(const float4*)&Wm2[r * 32 + c];
    }
    if (t < 64) b1s[t] = bm1[t];
    else if (t < 96) b2s[t - 64] = bm2[t - 64];

    int node0 = blockIdx.x * 64;
    {
        int f4 = (t & 15) * 4;
        int nl0 = t >> 4;
        for (int p = 0; p < 4; p++) {
            int nl = nl0 + p * 16;
            int node = node0 + nl;
            float4 v = make_float4(0.f, 0.f, 0.f, 0.f);
            if (node < N) v = *(const float4*)&H[(size_t)node * 64 + f4];
            *(float4*)&Hs[nl][f4] = v;
        }
    }
    __syncthreads();

    // GEMM1: hid = relu(Hs @ W1 + b1)
    float acc[4][4] = {{0}};
    int c4 = (t & 15) * 4;
    int r4 = (t >> 4) * 4;
#pragma unroll 4
    for (int k4 = 0; k4 < 64; k4 += 4) {
        float4 xv[4], wv[4];
#pragma unroll
        for (int i = 0; i < 4; i++) xv[i] = *(const float4*)&Hs[r4 + i][k4];
#pragma unroll
        for (int q = 0; q < 4; q++) wv[q] = *(const float4*)&W1s[k4 + q][c4];
#pragma unroll
        for (int i = 0; i < 4; i++) {
            acc[i][0] = fmaf(xv[i].x, wv[0].x, acc[i][0]);
            acc[i][1] = fmaf(xv[i].x, wv[0].y, acc[i][1]);
            acc[i][2] = fmaf(xv[i].x, wv[0].z, acc[i][2]);
            acc[i][3] = fmaf(xv[i].x, wv[0].w, acc[i][3]);
            acc[i][0] = fmaf(xv[i].y, wv[1].x, acc[i][0]);
            acc[i][1] = fmaf(xv[i].y, wv[1].y, acc[i][1]);
            acc[i][2] = fmaf(xv[i].y, wv[1].z, acc[i][2]);
            acc[i][3] = fmaf(xv[i].y, wv[1].w, acc[i][3]);
            acc[i][0] = fmaf(xv[i].z, wv[2].x, acc[i][0]);
            acc[i][1] = fmaf(xv[i].z, wv[2].y, acc[i][1]);
            acc[i][2] = fmaf(xv[i].z, wv[2].z, acc[i][2]);
            acc[i][3] = fmaf(xv[i].z, wv[2].w, acc[i][3]);
            acc[i][0] = fmaf(xv[i].w, wv[3].x, acc[i][0]);
            acc[i][1] = fmaf(xv[i].w, wv[3].y, acc[i][1]);
            acc[i][2] = fmaf(xv[i].w, wv[3].z, acc[i][2]);
            acc[i][3] = fmaf(xv[i].w, wv[3].w, acc[i][3]);
        }
    }
    __syncthreads();  // done reading Hs
#pragma unroll
    for (int i = 0; i < 4; i++) {
        float4 o;
        o.x = fmaxf(acc[i][0] + b1s[c4 + 0], 0.0f);
        o.y = fmaxf(acc[i][1] + b1s[c4 + 1], 0.0f);
        o.z = fmaxf(acc[i][2] + b1s[c4 + 2], 0.0f);
        o.w = fmaxf(acc[i][3] + b1s[c4 + 3], 0.0f);
        *(float4*)&Hs[r4 + i][c4] = o;  // hidden tile overwrites Hs
    }
    __syncthreads();

    // GEMM2: out = hid @ W2 + b2; thread = 2 nodes x 4 cols
    {
        int cc4 = (t & 7) * 4;
        int r2 = (t >> 3) * 2;
        float a2[2][4] = {{0}};
#pragma unroll 4
        for (int k4 = 0; k4 < 64; k4 += 4) {
            float4 xv[2], wv[4];
#pragma unroll
            for (int i = 0; i < 2; i++) xv[i] = *(const float4*)&Hs[r2 + i][k4];
#pragma unroll
            for (int q = 0; q < 4; q++) wv[q] = *(const float4*)&W2s[k4 + q][cc4];
#pragma unroll
            for (int i = 0; i < 2; i++) {
                a2[i][0] = fmaf(xv[i].x, wv[0].x, a2[i][0]);
                a2[i][1] = fmaf(xv[i].x, wv[0].y, a2[i][1]);
                a2[i][2] = fmaf(xv[i].x, wv[0].z, a2[i][2]);
                a2[i][3] = fmaf(xv[i].x, wv[0].w, a2[i][3]);
                a2[i][0] = fmaf(xv[i].y, wv[1].x, a2[i][0]);
                a2[i][1] = fmaf(xv[i].y, wv[1].y, a2[i][1]);
                a2[i][2] = fmaf(xv[i].y, wv[1].z, a2[i][2]);
                a2[i][3] = fmaf(xv[i].y, wv[1].w, a2[i][3]);
                a2[i][0] = fmaf(xv[i].z, wv[2].x, a2[i][0]);
                a2[i][1] = fmaf(xv[i].z, wv[2].y, a2[i][1]);
                a2[i][2] = fmaf(xv[i].z, wv[2].z, a2[i][2]);
                a2[i][3] = fmaf(xv[i].z, wv[2].w, a2[i][3]);
                a2[i][0] = fmaf(xv[i].w, wv[3].x, a2[i][0]);
                a2[i][1] = fmaf(xv[i].w, wv[3].y, a2[i][1]);
                a2[i][2] = fmaf(xv[i].w, wv[3].z, a2[i][2]);
                a2[i][3] = fmaf(xv[i].w, wv[3].w, a2[i][3]);
            }
        }
#pragma unroll
        for (int i = 0; i < 2; i++) {
            int row = node0 + r2 + i;
            if (row < N) {
                float4 o;
                o.x = a2[i][0] + b2s[cc4 + 0];
                o.y = a2[i][1] + b2s[cc4 + 1];
                o.z = a2[i][2] + b2s[cc4 + 2];
                o.w = a2[i][3] + b2s[cc4 + 3];
                *(float4*)&out[(size_t)row * 32 + cc4] = o;
            }
        }
    }
}

extern "C" void kernel_launch(void* const* d_in, const int* in_sizes, int n_in,
                              void* d_out, int out_size, void* d_ws, size_t ws_size,
                              hipStream_t stream) {
    const float* features = (const float*)d_in[0];
    const int* src = (const int*)d_in[1];
    const int* dst = (const int*)d_in[2];
    const float* W1 = (const float*)d_in[4];
    const float* b1 = (const float*)d_in[5];
    const float* W2 = (const float*)d_in[6];
    const float* b2 = (const float*)d_in[7];
    const float* Wm1 = (const float*)d_in[8];
    const float* bm1 = (const float*)d_in[9];
    const float* Wm2 = (const float*)d_in[10];
    const float* bm2 = (const float*)d_in[11];
    float* out = (float*)d_out;

    int N = in_sizes[0] / 64;
    int E = in_sizes[1];

    float* ws = (float*)d_ws;
    float* dinv = ws;
    float* B1 = ws + N;
    float* B2 = B1 + (size_t)N * 64;
    float* B3 = B2 + (size_t)N * 64;
    float* B4 = B3 + (size_t)N * 64;
    int* row_ptr = (int*)(B4 + (size_t)N * 64);
    int* cursor = row_ptr + (N + 1);
    int* bsum = cursor + N;
    int2* cw = (int2*)(((uintptr_t)(bsum + 1024) + 7) & ~(uintptr_t)7);

    int eblk = (E + 255) / 256;
    int nblk = (N + 255) / 256;
    int pblk = (N * 64 + 255) / 256;
    int gblk = (N + 63) / 64;

    hipMemsetAsync(cursor, 0, (size_t)N * sizeof(int), stream);
    k_hist<<<eblk, 256, 0, stream>>>(dst, cursor, E);
    k_blocksum<<<nblk, 256, 0, stream>>>(cursor, bsum, N);
    k_scanbsum<<<1, 1024, 0, stream>>>(bsum, nblk);
    k_scanfinal<<<nblk, 256, 0, stream>>>(cursor, bsum, row_ptr, cursor, dinv, N, E);
    k_place<<<eblk, 256, 0, stream>>>(src, dst, dinv, cursor, cw, E);

    k_prop<1><<<pblk, 256, 0, stream>>>(features, row_ptr, cw, dinv, nullptr, B1, N);
    k_prop<2><<<pblk, 256, 0, stream>>>(B1, row_ptr, cw, dinv, features, B2, N);
    k_cheb_gemm<<<gblk, 256, 0, stream>>>(features, B1, B2, W1, b1, B4, N);

    k_prop<1><<<pblk, 256, 0, stream>>>(B4, row_ptr, cw, dinv, nullptr, B1, N);
    k_prop<2><<<pblk, 256, 0, stream>>>(B1, row_ptr, cw, dinv, B4, B2, N);
    k_cheb_gemm<<<gblk, 256, 0, stream>>>(B4, B1, B2, W2, b2, B3, N);

    k_mlp_gemm<<<gblk, 256, 0, stream>>>(B3, Wm1, bm1, Wm2, bm2, out, N);
}